// Round 8
// baseline (34.928 us; speedup 1.0000x reference)
//
#include <hip/hip_runtime.h>
#include <math.h>

#define HH 256
#define WW 256
#define NTHREADS 256
#define CHUNKG 128            // gaussians per block (one slice)
#define HWPIX (HH * WW)
#define PADIDX(i) ((i) + ((i) >> 3))   // +1 float4 per 8 -> quadrant reads hit distinct banks

typedef short s8v __attribute__((ext_vector_type(8)));   // 8 bf16 (4 VGPRs)
typedef float f4v __attribute__((ext_vector_type(4)));   // MFMA accumulator

// pack two f32 as bf16 (truncate) into one u32: lo=first, hi=second
__device__ __forceinline__ unsigned pk_trunc(float lo, float hi) {
    return (__float_as_uint(hi) & 0xFFFF0000u) | (__float_as_uint(lo) >> 16);
}

// ---------------------------------------------------------------------------
// MFMA partial kernel. Block = one image row (y = blockIdx.x) x one slice of
// 128 gaussians (blockIdx.y). 4 waves, each owning 64 consecutive x.
// Exponent per gaussian expanded at staging for this row:
//   log2(alpha) = A*x^2 + B*x + E,  E = (A*y + C)*y + D
// GEMM via mfma_f32_16x16x32_bf16: A-frag = alpha (16 px x 32 g, bf16),
// B-frag = payload C[g][c], c in {1, r, g, b, z} (cols 5..15 zero).
// Both A and B use k = (lane>>4)*8 + j per-lane enumeration (consistent ->
// immune to within-lane k permutation). D: col=lane&15, row=(lane>>4)*4+reg.
// ---------------------------------------------------------------------------
__global__ __launch_bounds__(NTHREADS) void partial_kernel(
    const float* __restrict__ means,
    const float* __restrict__ colors,
    const float* __restrict__ opacity,
    const float* __restrict__ scales,
    const float* __restrict__ K,
    const float* __restrict__ M,
    float* __restrict__ outp,
    int N)
{
    __shared__ float4   prm[PADIDX(CHUNKG - 1) + 1];   // {A, B, E, 0}, padded
    __shared__ float4   colf[CHUNKG];                  // {r, g, b, z}
    __shared__ unsigned bfr[(CHUNKG / 32) * 256];      // B-frags

    const int tid = threadIdx.x;
    const int y   = blockIdx.x;
    const int g0  = blockIdx.y * CHUNKG;
    const float yf = (float)y;

    // ---- Phase 1: project this slice's gaussians (threads 0..127) ----
    if (tid < CHUNKG) {
        const int n = g0 + tid;
        float A = 0.f, Bc = 0.f, E = -INFINITY;
        float4 cf = make_float4(0.f, 0.f, 0.f, 0.f);
        if (n < N) {
            const float wx = means[3 * n + 0];
            const float wy = means[3 * n + 1];
            const float wz = means[3 * n + 2];
            const float px = M[0] * wx + M[1] * wy + M[2]  * wz + M[3];
            const float py = M[4] * wx + M[5] * wy + M[6]  * wz + M[7];
            const float pz = M[8] * wx + M[9] * wy + M[10] * wz + M[11];
            const float rz = 1.0f / pz;
            const float u  = (K[0] * px + K[1] * py + K[2] * pz) * rz;
            const float v  = (K[4] * py + K[5] * pz) * rz;
            const bool valid = (pz > 1e-4f)
                            && (u >= -(float)WW) && (u <= 2.0f * (float)WW)
                            && (v >= -(float)HH) && (v <= 2.0f * (float)HH);
            if (valid) {
                const float op  = opacity[n];
                const float sig = fmaxf(scales[n] * 256.0f, 1.0f);
                const float coef = -0.72134752044448170368f / (sig * sig); // -0.5*log2e/sig^2
                A  = coef;
                Bc = -2.0f * coef * u;
                const float C = -2.0f * coef * v;
                const float D = fmaf(coef, fmaf(u, u, v * v), __log2f(op)); // op=0 -> -inf
                E  = fmaf(fmaf(A, yf, C), yf, D);
                cf = make_float4(colors[3 * n + 0], colors[3 * n + 1],
                                 colors[3 * n + 2], pz);
            }
        }
        prm[PADIDX(tid)] = make_float4(A, Bc, E, 0.f);
        colf[tid] = cf;
    }
    __syncthreads();

    // ---- Phase 2: build B-fragments (payload matrix in MFMA B layout) ----
    for (int e = tid; e < (CHUNKG / 32) * 256; e += NTHREADS) {
        const int lane6 = (e >> 2) & 63;
        const int reg   = e & 3;
        const int kl    = ((e >> 8) << 5) + ((lane6 >> 4) << 3) + (reg << 1);
        const int col   = lane6 & 15;
        const float4 c0 = colf[kl];
        const float4 c1 = colf[kl + 1];
        const float lo = (col == 0) ? 1.f : (col == 1) ? c0.x : (col == 2) ? c0.y
                       : (col == 3) ? c0.z : (col == 4) ? c0.w : 0.f;
        const float hi = (col == 0) ? 1.f : (col == 1) ? c1.x : (col == 2) ? c1.y
                       : (col == 3) ? c1.z : (col == 4) ? c1.w : 0.f;
        bfr[e] = pk_trunc(lo, hi);
    }
    __syncthreads();

    // ---- Phase 3: alpha eval + MFMA accumulate ----
    const int lane = tid & 63;
    const int wv   = tid >> 6;          // wave covers x in [wv*64, wv*64+64)
    const int kq   = (lane >> 4) << 3;  // this lane's k-block base (0,8,16,24)

    f4v acc[4];
    #pragma unroll
    for (int t = 0; t < 4; ++t) acc[t] = (f4v){0.f, 0.f, 0.f, 0.f};

    float xs[4], xxs[4];
    #pragma unroll
    for (int t = 0; t < 4; ++t) {
        xs[t]  = (float)(wv * 64 + t * 16 + (lane & 15));
        xxs[t] = xs[t] * xs[t];
    }

    #pragma unroll
    for (int c = 0; c < CHUNKG / 32; ++c) {
        float4 P[8];
        #pragma unroll
        for (int j = 0; j < 8; ++j) P[j] = prm[PADIDX(c * 32 + kq) + j];

        union { s8v v; uint4 q; } Bf;
        Bf.q = *(const uint4*)&bfr[c * 256 + lane * 4];

        #pragma unroll
        for (int t = 0; t < 4; ++t) {
            union { s8v v; unsigned u[4]; } Af;
            #pragma unroll
            for (int r = 0; r < 4; ++r) {
                const float4 p0 = P[2 * r];
                const float4 p1 = P[2 * r + 1];
                const float a0 = fminf(exp2f(fmaf(p0.y, xs[t], fmaf(p0.x, xxs[t], p0.z))), 0.95f);
                const float a1 = fminf(exp2f(fmaf(p1.y, xs[t], fmaf(p1.x, xxs[t], p1.z))), 0.95f);
                Af.u[r] = pk_trunc(a0, a1);
            }
            acc[t] = __builtin_amdgcn_mfma_f32_16x16x32_bf16(Af.v, Bf.v, acc[t], 0, 0, 0);
        }
    }

    // ---- Store: lane holds payload col=lane&15 for rows (lane>>4)*4+r ----
    const int col = lane & 15;
    if (col < 5) {
        float* pl = outp + ((size_t)blockIdx.y * 5 + col) * HWPIX + (size_t)y * WW;
        const int rb = (lane >> 4) << 2;
        #pragma unroll
        for (int t = 0; t < 4; ++t) {
            #pragma unroll
            for (int r = 0; r < 4; ++r) {
                pl[wv * 64 + t * 16 + rb + r] = acc[t][r];
            }
        }
    }
}

// ---------------------------------------------------------------------------
// Epilogue: float4-vectorized. Each thread owns 4 consecutive pixels.
// Partials layout: [slice][payload(S,r,g,b,z)][pixel]
// ---------------------------------------------------------------------------
__global__ __launch_bounds__(128) void epilogue_kernel(
    const float4* __restrict__ outp4, float4* __restrict__ out4, int nslice)
{
    const int p4 = blockIdx.x * 128 + threadIdx.x;     // 0..16383
    const int Q  = HWPIX / 4;                          // float4s per plane
    float4 s  = make_float4(0.f, 0.f, 0.f, 0.f);
    float4 ar = s, ag = s, ab = s, az = s;
    for (int sl = 0; sl < nslice; ++sl) {
        const float4* o = outp4 + (size_t)(sl * 5) * Q + p4;
        const float4 v0 = o[0 * Q], v1 = o[1 * Q], v2 = o[2 * Q],
                     v3 = o[3 * Q], v4 = o[4 * Q];
        s.x  += v0.x; s.y  += v0.y; s.z  += v0.z; s.w  += v0.w;
        ar.x += v1.x; ar.y += v1.y; ar.z += v1.z; ar.w += v1.w;
        ag.x += v2.x; ag.y += v2.y; ag.z += v2.z; ag.w += v2.w;
        ab.x += v3.x; ab.y += v3.y; ab.z += v3.z; ab.w += v3.w;
        az.x += v4.x; az.y += v4.y; az.z += v4.z; az.w += v4.w;
    }
    float4 R, G, B, AC, DZ;
    float* sp = (float*)&s;  float* arp = (float*)&ar; float* agp = (float*)&ag;
    float* abp = (float*)&ab; float* azp = (float*)&az;
    float* Rp = (float*)&R;  float* Gp = (float*)&G;  float* Bp = (float*)&B;
    float* Ap = (float*)&AC; float* Dp = (float*)&DZ;
    #pragma unroll
    for (int i = 0; i < 4; ++i) {
        const float inv   = 1.0f / (sp[i] + 1e-6f);
        const float accum = fminf(sp[i], 1.0f);
        const float bg    = 1.0f - accum;
        Rp[i] = fminf(fmaxf(fmaf(arp[i] * inv, accum, bg), 0.0f), 1.0f);
        Gp[i] = fminf(fmaxf(fmaf(agp[i] * inv, accum, bg), 0.0f), 1.0f);
        Bp[i] = fminf(fmaxf(fmaf(abp[i] * inv, accum, bg), 0.0f), 1.0f);
        Ap[i] = accum;
        Dp[i] = azp[i] * inv;
    }
    out4[0 * Q + p4] = R;
    out4[1 * Q + p4] = G;
    out4[2 * Q + p4] = B;
    out4[3 * Q + p4] = AC;
    out4[4 * Q + p4] = DZ;
}

// ---------------------------------------------------------------------------
// Fallback fused kernel (only if ws is too small) — known-good round-2 path.
// ---------------------------------------------------------------------------
__global__ __launch_bounds__(NTHREADS) void fused_kernel(
    const float* __restrict__ means,
    const float* __restrict__ colors,
    const float* __restrict__ opacity,
    const float* __restrict__ scales,
    const float* __restrict__ K,
    const float* __restrict__ M,
    float* __restrict__ out,
    int N)
{
    __shared__ float4 sg[256 * 2];
    const int tid = threadIdx.x;
    const int p   = blockIdx.x * NTHREADS + tid;
    const float x = (float)(p & (WW - 1));
    const float y = (float)(p >> 8);
    const float fx = K[0], sk = K[1], cx = K[2], fy = K[4], cy = K[5];

    float s = 0.f, ar = 0.f, ag = 0.f, ab = 0.f, az = 0.f;
    for (int base = 0; base < N; base += 256) {
        const int cnt = min(256, N - base);
        __syncthreads();
        for (int i = tid; i < cnt; i += NTHREADS) {
            const int n = base + i;
            const float wx = means[3 * n + 0];
            const float wy = means[3 * n + 1];
            const float wz = means[3 * n + 2];
            const float px = M[0] * wx + M[1] * wy + M[2]  * wz + M[3];
            const float py = M[4] * wx + M[5] * wy + M[6]  * wz + M[7];
            const float pz = M[8] * wx + M[9] * wy + M[10] * wz + M[11];
            const float rz = 1.0f / pz;
            float u = (fx * px + sk * py + cx * pz) * rz;
            float v = (fy * py + cy * pz) * rz;
            const bool valid = (pz > 1e-4f)
                            && (u >= -(float)WW) && (u <= 2.0f * (float)WW)
                            && (v >= -(float)HH) && (v <= 2.0f * (float)HH);
            const float op = valid ? opacity[n] : 0.0f;
            const float sig = fmaxf(scales[n] * 256.0f, 1.0f);
            float coef = -0.72134752044448170368f / (sig * sig);
            const float lop = __log2f(op);
            float uu = valid ? u : 0.f, vv = valid ? v : 0.f;
            float cf = valid ? coef : 0.f;
            sg[2 * i + 0] = make_float4(uu, vv, cf, lop);
            sg[2 * i + 1] = make_float4(colors[3 * n + 0], colors[3 * n + 1],
                                        colors[3 * n + 2], pz);
        }
        __syncthreads();
        for (int n = 0; n < cnt; ++n) {
            const float4 a = sg[2 * n + 0];
            const float4 c = sg[2 * n + 1];
            const float dx = x - a.x, dy = y - a.y;
            const float r2 = fmaf(dy, dy, dx * dx);
            const float alpha = fminf(exp2f(fmaf(r2, a.z, a.w)), 0.95f);
            s += alpha;
            ar = fmaf(alpha, c.x, ar); ag = fmaf(alpha, c.y, ag);
            ab = fmaf(alpha, c.z, ab); az = fmaf(alpha, c.w, az);
        }
    }
    const float inv   = 1.0f / (s + 1e-6f);
    const float accum = fminf(s, 1.0f);
    const float bg    = 1.0f - accum;
    out[0 * HWPIX + p] = fminf(fmaxf(fmaf(ar * inv, accum, bg), 0.0f), 1.0f);
    out[1 * HWPIX + p] = fminf(fmaxf(fmaf(ag * inv, accum, bg), 0.0f), 1.0f);
    out[2 * HWPIX + p] = fminf(fmaxf(fmaf(ab * inv, accum, bg), 0.0f), 1.0f);
    out[3 * HWPIX + p] = accum;
    out[4 * HWPIX + p] = az * inv;
}

extern "C" void kernel_launch(void* const* d_in, const int* in_sizes, int n_in,
                              void* d_out, int out_size, void* d_ws, size_t ws_size,
                              hipStream_t stream) {
    const float* means      = (const float*)d_in[0];
    const float* colors     = (const float*)d_in[1];
    const float* opacity    = (const float*)d_in[2];
    const float* scales     = (const float*)d_in[3];
    const float* intrinsics = (const float*)d_in[4];
    const float* w2c        = (const float*)d_in[5];
    float* out = (float*)d_out;
    float* ws  = (float*)d_ws;

    const int N = in_sizes[0] / 3;
    const int nslice = (N + CHUNKG - 1) / CHUNKG;   // 8 for N=1024

    if ((size_t)nslice * 5 * HWPIX * 4 > ws_size) {
        fused_kernel<<<HWPIX / NTHREADS, NTHREADS, 0, stream>>>(
            means, colors, opacity, scales, intrinsics, w2c, out, N);
        return;
    }

    dim3 grid(HH, nslice);   // 256 rows x 8 slices = 2048 blocks -> 8/CU
    partial_kernel<<<grid, NTHREADS, 0, stream>>>(
        means, colors, opacity, scales, intrinsics, w2c, ws, N);
    epilogue_kernel<<<HWPIX / 4 / 128, 128, 0, stream>>>(
        (const float4*)ws, (float4*)out, nslice);
}

// Round 10
// 22.734 us; speedup vs baseline: 1.5364x; 1.5364x over previous
//
#include <hip/hip_runtime.h>
#include <math.h>

#define HH 256
#define WW 256
#define NTHREADS 256
#define CHUNKG 128            // gaussians per block-slice (before culling)
#define HWPIX (HH * WW)
#define PADIDX(i) ((i) + ((i) >> 3))   // quadrant reads hit distinct banks
#define ECUT (-15.0f)                  // drop gaussians whose ROW-PEAK log2(alpha) < ECUT

typedef short s8v __attribute__((ext_vector_type(8)));   // 8 bf16 (4 VGPRs)
typedef float f4v __attribute__((ext_vector_type(4)));   // MFMA accumulator

// pack two f32 as bf16 (truncate) into one u32: lo=first, hi=second
__device__ __forceinline__ unsigned pk_trunc(float lo, float hi) {
    return (__float_as_uint(hi) & 0xFFFF0000u) | (__float_as_uint(lo) >> 16);
}
// raw v_exp_f32 (exp2): -inf -> 0, no libcall edge handling
__device__ __forceinline__ float fexp2(float x) {
    return __builtin_amdgcn_exp2f(x);
}

// ---------------------------------------------------------------------------
// MFMA partial kernel. Block = one image row (y = blockIdx.x) x one slice of
// 128 gaussians (blockIdx.y). 4 waves, each owning 64 consecutive x.
// Per-row culling: the row-peak of log2(alpha) (attained at x=u) is
//   rowpeak = coef*(y-v)^2 + log2(op)        <-- NOT E (R9 bug: E=A*u^2+rowpeak)
// Survivors (rowpeak > ECUT) are compacted into LDS via ballot+popcount and
// padded to a multiple of 32 with E=-inf dummies (exp2 -> exact 0).
//   log2(alpha) = A*x^2 + B*x + E,  E = (A*y + C)*y + D
// GEMM via mfma_f32_16x16x32_bf16: A-frag = alpha (16 px x 32 g, bf16),
// B-frag = payload C[g][c], c in {1, r, g, b, z}. Both use the same k
// enumeration k=(lane>>4)*8+j. D: col=lane&15, row=(lane>>4)*4+reg.
// ---------------------------------------------------------------------------
__global__ __launch_bounds__(NTHREADS, 6) void partial_kernel(
    const float* __restrict__ means,
    const float* __restrict__ colors,
    const float* __restrict__ opacity,
    const float* __restrict__ scales,
    const float* __restrict__ K,
    const float* __restrict__ M,
    float* __restrict__ outp,
    int N)
{
    __shared__ float4   prm[PADIDX(CHUNKG - 1) + 1];   // {A, B, E, 0}, padded idx
    __shared__ float4   colf[CHUNKG];                  // {r, g, b, z}
    __shared__ unsigned bfr[(CHUNKG / 32) * 256];      // B-frags
    __shared__ int      scnt[2];                       // per-wave survivor counts

    const int tid = threadIdx.x;
    const int y   = blockIdx.x;
    const int g0  = blockIdx.y * CHUNKG;
    const float yf = (float)y;

    // ---- Phase 1a: project + cull flag (threads 0..127) ----
    float A = 0.f, Bc = 0.f, E = -INFINITY;
    float4 cf = make_float4(0.f, 0.f, 0.f, 0.f);
    bool keep = false;
    int prefix = 0;
    if (tid < CHUNKG) {
        const int n = g0 + tid;
        float rowpeak = -INFINITY;
        if (n < N) {
            const float wx = means[3 * n + 0];
            const float wy = means[3 * n + 1];
            const float wz = means[3 * n + 2];
            const float px = M[0] * wx + M[1] * wy + M[2]  * wz + M[3];
            const float py = M[4] * wx + M[5] * wy + M[6]  * wz + M[7];
            const float pz = M[8] * wx + M[9] * wy + M[10] * wz + M[11];
            const float rz = 1.0f / pz;
            const float u  = (K[0] * px + K[1] * py + K[2] * pz) * rz;
            const float v  = (K[4] * py + K[5] * pz) * rz;
            const bool valid = (pz > 1e-4f)
                            && (u >= -(float)WW) && (u <= 2.0f * (float)WW)
                            && (v >= -(float)HH) && (v <= 2.0f * (float)HH);
            if (valid) {
                const float op  = opacity[n];
                const float sig = fmaxf(scales[n] * 256.0f, 1.0f);
                const float coef = -0.72134752044448170368f / (sig * sig); // -0.5*log2e/sig^2
                const float lop = __log2f(op);                  // op=0 -> -inf
                const float dyv = yf - v;
                rowpeak = fmaf(coef, dyv * dyv, lop);           // true row-max of log2(alpha)
                A  = coef;
                Bc = -2.0f * coef * u;
                const float C = -2.0f * coef * v;
                const float D = fmaf(coef, fmaf(u, u, v * v), lop);
                E  = fmaf(fmaf(A, yf, C), yf, D);
                cf = make_float4(colors[3 * n + 0], colors[3 * n + 1],
                                 colors[3 * n + 2], pz);
            }
        }
        keep = (rowpeak > ECUT);
        const unsigned long long mask = __ballot(keep);
        const int lane = tid & 63;
        prefix = __popcll(mask & ((1ull << lane) - 1ull));
        if (lane == 0) scnt[tid >> 6] = __popcll(mask);
    }
    __syncthreads();

    const int cnt0   = scnt[0];
    const int cnt    = cnt0 + scnt[1];
    const int padded = (cnt + 31) & ~31;
    const int nch    = padded >> 5;

    // ---- Phase 1b: compacted writes + pad dummies ----
    if (tid < CHUNKG && keep) {
        const int pos = ((tid >> 6) ? cnt0 : 0) + prefix;
        prm[PADIDX(pos)] = make_float4(A, Bc, E, 0.f);
        colf[pos] = cf;
    }
    if (tid < padded - cnt) {
        const int pos = cnt + tid;
        prm[PADIDX(pos)] = make_float4(0.f, 0.f, -INFINITY, 0.f);
        colf[pos] = make_float4(0.f, 0.f, 0.f, 0.f);
    }
    __syncthreads();

    // ---- Phase 2: build B-fragments (payload matrix in MFMA B layout) ----
    for (int e = tid; e < nch * 256; e += NTHREADS) {
        const int lane6 = (e >> 2) & 63;
        const int reg   = e & 3;
        const int kl    = ((e >> 8) << 5) + ((lane6 >> 4) << 3) + (reg << 1);
        const int col   = lane6 & 15;
        const float4 c0 = colf[kl];
        const float4 c1 = colf[kl + 1];
        const float lo = (col == 0) ? 1.f : (col == 1) ? c0.x : (col == 2) ? c0.y
                       : (col == 3) ? c0.z : (col == 4) ? c0.w : 0.f;
        const float hi = (col == 0) ? 1.f : (col == 1) ? c1.x : (col == 2) ? c1.y
                       : (col == 3) ? c1.z : (col == 4) ? c1.w : 0.f;
        bfr[e] = pk_trunc(lo, hi);
    }
    __syncthreads();

    // ---- Phase 3: alpha eval + MFMA accumulate over surviving chunks ----
    const int lane = tid & 63;
    const int wv   = tid >> 6;          // wave covers x in [wv*64, wv*64+64)
    const int kq   = (lane >> 4) << 3;  // this lane's k-block base (0,8,16,24)

    f4v acc[4];
    #pragma unroll
    for (int t = 0; t < 4; ++t) acc[t] = (f4v){0.f, 0.f, 0.f, 0.f};

    float xs[4], xxs[4];
    #pragma unroll
    for (int t = 0; t < 4; ++t) {
        xs[t]  = (float)(wv * 64 + t * 16 + (lane & 15));
        xxs[t] = xs[t] * xs[t];
    }

    for (int c = 0; c < nch; ++c) {
        float4 P[8];
        #pragma unroll
        for (int j = 0; j < 8; ++j) P[j] = prm[PADIDX(c * 32 + kq) + j];

        union { s8v v; uint4 q; } Bf;
        Bf.q = *(const uint4*)&bfr[c * 256 + lane * 4];

        #pragma unroll
        for (int t = 0; t < 4; ++t) {
            union { s8v v; unsigned u[4]; } Af;
            #pragma unroll
            for (int r = 0; r < 4; ++r) {
                const float4 p0 = P[2 * r];
                const float4 p1 = P[2 * r + 1];
                const float a0 = fminf(fexp2(fmaf(p0.y, xs[t], fmaf(p0.x, xxs[t], p0.z))), 0.95f);
                const float a1 = fminf(fexp2(fmaf(p1.y, xs[t], fmaf(p1.x, xxs[t], p1.z))), 0.95f);
                Af.u[r] = pk_trunc(a0, a1);
            }
            acc[t] = __builtin_amdgcn_mfma_f32_16x16x32_bf16(Af.v, Bf.v, acc[t], 0, 0, 0);
        }
    }

    // ---- Store: lane holds payload col=lane&15 for rows (lane>>4)*4+r ----
    const int col = lane & 15;
    if (col < 5) {
        float* pl = outp + ((size_t)blockIdx.y * 5 + col) * HWPIX + (size_t)y * WW;
        const int rb = (lane >> 4) << 2;
        #pragma unroll
        for (int t = 0; t < 4; ++t) {
            #pragma unroll
            for (int r = 0; r < 4; ++r) {
                pl[wv * 64 + t * 16 + rb + r] = acc[t][r];
            }
        }
    }
}

// ---------------------------------------------------------------------------
// Epilogue: float4-vectorized. Each thread owns 4 consecutive pixels.
// Partials layout: [slice][payload(S,r,g,b,z)][pixel]
// ---------------------------------------------------------------------------
__global__ __launch_bounds__(128) void epilogue_kernel(
    const float4* __restrict__ outp4, float4* __restrict__ out4, int nslice)
{
    const int p4 = blockIdx.x * 128 + threadIdx.x;     // 0..16383
    const int Q  = HWPIX / 4;                          // float4s per plane
    float4 s  = make_float4(0.f, 0.f, 0.f, 0.f);
    float4 ar = s, ag = s, ab = s, az = s;
    for (int sl = 0; sl < nslice; ++sl) {
        const float4* o = outp4 + (size_t)(sl * 5) * Q + p4;
        const float4 v0 = o[0 * Q], v1 = o[1 * Q], v2 = o[2 * Q],
                     v3 = o[3 * Q], v4 = o[4 * Q];
        s.x  += v0.x; s.y  += v0.y; s.z  += v0.z; s.w  += v0.w;
        ar.x += v1.x; ar.y += v1.y; ar.z += v1.z; ar.w += v1.w;
        ag.x += v2.x; ag.y += v2.y; ag.z += v2.z; ag.w += v2.w;
        ab.x += v3.x; ab.y += v3.y; ab.z += v3.z; ab.w += v3.w;
        az.x += v4.x; az.y += v4.y; az.z += v4.z; az.w += v4.w;
    }
    float4 R, G, B, AC, DZ;
    float* sp = (float*)&s;  float* arp = (float*)&ar; float* agp = (float*)&ag;
    float* abp = (float*)&ab; float* azp = (float*)&az;
    float* Rp = (float*)&R;  float* Gp = (float*)&G;  float* Bp = (float*)&B;
    float* Ap = (float*)&AC; float* Dp = (float*)&DZ;
    #pragma unroll
    for (int i = 0; i < 4; ++i) {
        const float inv   = 1.0f / (sp[i] + 1e-6f);
        const float accum = fminf(sp[i], 1.0f);
        const float bg    = 1.0f - accum;
        Rp[i] = fminf(fmaxf(fmaf(arp[i] * inv, accum, bg), 0.0f), 1.0f);
        Gp[i] = fminf(fmaxf(fmaf(agp[i] * inv, accum, bg), 0.0f), 1.0f);
        Bp[i] = fminf(fmaxf(fmaf(abp[i] * inv, accum, bg), 0.0f), 1.0f);
        Ap[i] = accum;
        Dp[i] = azp[i] * inv;
    }
    out4[0 * Q + p4] = R;
    out4[1 * Q + p4] = G;
    out4[2 * Q + p4] = B;
    out4[3 * Q + p4] = AC;
    out4[4 * Q + p4] = DZ;
}

// ---------------------------------------------------------------------------
// Fallback fused kernel (only if ws is too small) — round-2 path + fast exp2.
// ---------------------------------------------------------------------------
__global__ __launch_bounds__(NTHREADS) void fused_kernel(
    const float* __restrict__ means,
    const float* __restrict__ colors,
    const float* __restrict__ opacity,
    const float* __restrict__ scales,
    const float* __restrict__ K,
    const float* __restrict__ M,
    float* __restrict__ out,
    int N)
{
    __shared__ float4 sg[256 * 2];
    const int tid = threadIdx.x;
    const int p   = blockIdx.x * NTHREADS + tid;
    const float x = (float)(p & (WW - 1));
    const float y = (float)(p >> 8);
    const float fx = K[0], sk = K[1], cx = K[2], fy = K[4], cy = K[5];

    float s = 0.f, ar = 0.f, ag = 0.f, ab = 0.f, az = 0.f;
    for (int base = 0; base < N; base += 256) {
        const int cnt = min(256, N - base);
        __syncthreads();
        for (int i = tid; i < cnt; i += NTHREADS) {
            const int n = base + i;
            const float wx = means[3 * n + 0];
            const float wy = means[3 * n + 1];
            const float wz = means[3 * n + 2];
            const float px = M[0] * wx + M[1] * wy + M[2]  * wz + M[3];
            const float py = M[4] * wx + M[5] * wy + M[6]  * wz + M[7];
            const float pz = M[8] * wx + M[9] * wy + M[10] * wz + M[11];
            const float rz = 1.0f / pz;
            float u = (fx * px + sk * py + cx * pz) * rz;
            float v = (fy * py + cy * pz) * rz;
            const bool valid = (pz > 1e-4f)
                            && (u >= -(float)WW) && (u <= 2.0f * (float)WW)
                            && (v >= -(float)HH) && (v <= 2.0f * (float)HH);
            const float op = valid ? opacity[n] : 0.0f;
            const float sig = fmaxf(scales[n] * 256.0f, 1.0f);
            float coef = -0.72134752044448170368f / (sig * sig);
            const float lop = __log2f(op);
            float uu = valid ? u : 0.f, vv = valid ? v : 0.f;
            float cfv = valid ? coef : 0.f;
            sg[2 * i + 0] = make_float4(uu, vv, cfv, lop);
            sg[2 * i + 1] = make_float4(colors[3 * n + 0], colors[3 * n + 1],
                                        colors[3 * n + 2], pz);
        }
        __syncthreads();
        for (int n = 0; n < cnt; ++n) {
            const float4 a = sg[2 * n + 0];
            const float4 c = sg[2 * n + 1];
            const float dx = x - a.x, dy = y - a.y;
            const float r2 = fmaf(dy, dy, dx * dx);
            const float alpha = fminf(fexp2(fmaf(r2, a.z, a.w)), 0.95f);
            s += alpha;
            ar = fmaf(alpha, c.x, ar); ag = fmaf(alpha, c.y, ag);
            ab = fmaf(alpha, c.z, ab); az = fmaf(alpha, c.w, az);
        }
    }
    const float inv   = 1.0f / (s + 1e-6f);
    const float accum = fminf(s, 1.0f);
    const float bg    = 1.0f - accum;
    out[0 * HWPIX + p] = fminf(fmaxf(fmaf(ar * inv, accum, bg), 0.0f), 1.0f);
    out[1 * HWPIX + p] = fminf(fmaxf(fmaf(ag * inv, accum, bg), 0.0f), 1.0f);
    out[2 * HWPIX + p] = fminf(fmaxf(fmaf(ab * inv, accum, bg), 0.0f), 1.0f);
    out[3 * HWPIX + p] = accum;
    out[4 * HWPIX + p] = az * inv;
}

extern "C" void kernel_launch(void* const* d_in, const int* in_sizes, int n_in,
                              void* d_out, int out_size, void* d_ws, size_t ws_size,
                              hipStream_t stream) {
    const float* means      = (const float*)d_in[0];
    const float* colors     = (const float*)d_in[1];
    const float* opacity    = (const float*)d_in[2];
    const float* scales     = (const float*)d_in[3];
    const float* intrinsics = (const float*)d_in[4];
    const float* w2c        = (const float*)d_in[5];
    float* out = (float*)d_out;
    float* ws  = (float*)d_ws;

    const int N = in_sizes[0] / 3;
    const int nslice = (N + CHUNKG - 1) / CHUNKG;   // 8 for N=1024

    if ((size_t)nslice * 5 * HWPIX * 4 > ws_size) {
        fused_kernel<<<HWPIX / NTHREADS, NTHREADS, 0, stream>>>(
            means, colors, opacity, scales, intrinsics, w2c, out, N);
        return;
    }

    dim3 grid(HH, nslice);   // 256 rows x 8 slices = 2048 blocks -> 8/CU
    partial_kernel<<<grid, NTHREADS, 0, stream>>>(
        means, colors, opacity, scales, intrinsics, w2c, ws, N);
    epilogue_kernel<<<HWPIX / 4 / 128, 128, 0, stream>>>(
        (const float4*)ws, (float4*)out, nslice);
}